// Round 10
// baseline (101.319 us; speedup 1.0000x reference)
//
#include <hip/hip_runtime.h>
#include <hip/hip_bf16.h>
#include <cmath>
#include <cstdint>

#define Bsz   4096
#define INsz  512
#define OUTsz 512
#define NRING 16
#define KTOT  8704          /* IN*(NR+1): residual folded in as 17th slot */
#define SPLITK 8
#define NPH   34            /* 17 rings x 2 i-halves; B-tile K=32 each */

using short8 = __attribute__((ext_vector_type(8))) short;
using f32x4  = __attribute__((ext_vector_type(4))) float;

struct RC {
  float Fr[NRING];    // fract(rev0_r)
  float K2, SQ, pad0, pad1;  // h=K2*xc*rcp(wl); A' = rcp(cos2pi(fract(h+Fr))+SQ)
};

__device__ __forceinline__ unsigned short f2bf(float f) {
  __hip_bfloat16 h = __float2bfloat16(f);               // native cvt (RNE)
  return *reinterpret_cast<unsigned short*>(&h);
}
__device__ __forceinline__ float bf2f(unsigned short u) {
  union { unsigned int u; float f; } v; v.u = (unsigned int)u << 16;
  return v.f;
}
__device__ __forceinline__ float fastrcp(float x) {
#if __has_builtin(__builtin_amdgcn_rcpf)
  return __builtin_amdgcn_rcpf(x);
#else
  return 1.0f / x;
#endif
}
__device__ __forceinline__ float fastfract(float x) {
#if __has_builtin(__builtin_amdgcn_fractf)
  return __builtin_amdgcn_fractf(x);
#else
  return x - floorf(x);
#endif
}
__device__ __forceinline__ float cos2pi(float fr) {
#if __has_builtin(__builtin_amdgcn_cosf)
  return __builtin_amdgcn_cosf(fr);
#else
  return __cosf(fr * 6.28318530717958647692f);
#endif
}

__device__ __forceinline__ void gl_lds16(const void* g, void* l) {
  __builtin_amdgcn_global_load_lds(
      (const __attribute__((address_space(1))) void*)g,
      (__attribute__((address_space(3))) void*)l, 16, 0, 0);
}

// ---- pack B'^T: [OUT][KTOT] bf16, k = n*512 + i; also bias[o] = sum coeffs ----
__global__ __launch_bounds__(512) void pack_b_kernel(
    const float* __restrict__ coeffs, const float* __restrict__ bw,
    unsigned short* __restrict__ Bt, float* __restrict__ bias, float PQ) {
  __shared__ float red[8];
  const int o = blockIdx.x;        // 512 blocks
  const int i = threadIdx.x;       // 512 threads
  const float* cp = coeffs + ((size_t)i * OUTsz + o) * NRING;  // 64B contiguous
  unsigned short* row = Bt + (size_t)o * KTOT + i;
  float s = 0.0f;
#pragma unroll
  for (int j = 0; j < 4; ++j) {
    f32x4 v = *reinterpret_cast<const f32x4*>(cp + j * 4);
#pragma unroll
    for (int e = 0; e < 4; ++e) {
      const int n = j * 4 + e;
      s += v[e];
      row[(size_t)n * INsz] = f2bf(PQ * v[e]);
    }
  }
  row[(size_t)NRING * INsz] = f2bf(bw[(size_t)i * OUTsz + o]);  // residual unscaled
#pragma unroll
  for (int off = 32; off > 0; off >>= 1) s += __shfl_down(s, off);
  const int w = i >> 6;
  if ((i & 63) == 0) red[w] = s;
  __syncthreads();
  if (i == 0) {
    float t = 0.0f;
#pragma unroll
    for (int k = 0; k < 8; ++k) t += red[k];
    bias[o] = t;
  }
}

// ---- fused basis-gen + split-K bf16 MFMA GEMM ----
// Block 128x256 out, 256 thr (4 waves, wave tile 128x64), splitK=8
// -> grid 512 = 2 blocks/CU (80KB LDS, VGPR cap 256 via launch_bounds(256,2)).
// 34 sub-phases: ring = p>>1, i-half h = p&1. A-tile [128][64] per ring
// (dbuf x2, row&7 XOR swizzle); B-tile [256][32] (3-deep, mod-4 additive
// swizzle for 64B rows). Counted vmcnt(4), one barrier per sub-phase.
__global__ __launch_bounds__(256, 2) void gemm_fused_kernel(
    const float* __restrict__ x, const unsigned short* __restrict__ Bt,
    unsigned short* __restrict__ part, RC rc) {
  extern __shared__ char smem[];
  char* smA = smem;            // 2 x 16384 (128 rows x 128B)
  char* smB = smem + 32768;    // 3 x 16384 (256 rows x 64B)
  const int tid  = threadIdx.x;
  const int lane = tid & 63;
  const int w    = tid >> 6;         // 0..3 (wave = N-column block)
  const int bid  = blockIdx.x;
  const int combo = bid & 15;        // (cb,ks); same combo -> same XCD
  const int rb   = bid >> 4;         // 0..31
  const int cb   = combo & 1, ks = combo >> 1;   // cb 0..1, ks 0..7
  const int brow = rb * 128, bcol = cb * 256;

  // --- A-gen ownership: row r (0..127), i-half ih (32 of the 64 i's) ---
  const int r  = tid & 127;
  const int ih = tid >> 7;           // 0..1
  int wb[4];
#pragma unroll
  for (int g = 0; g < 4; ++g)
    wb[g] = r * 128 + (((ih * 4 + g) ^ (r & 7)) * 16);
  const float* gx = x + (size_t)(brow + r) * INsz + ks * 64 + ih * 32;

  // --- B staging: per-lane inverse-swizzled global source, linear LDS dest ---
  // dest (per gl_lds round iss): row = iss*64 + (tid>>2), oct = tid&3.
  const int drow = tid >> 2;                         // + iss*64
  const int doct = tid & 3;
  // --- fragment read geometry ---
  const int l7 = lane & 7;
  const int rowA = lane & 15;                        // + m*16
  const int rowBl = w * 64 + (lane & 15);            // + q*16 (local B row)
  const int ogB  = lane >> 4;                        // B global octet (K=32)
  const int olB  = (ogB + rowBl + (rowBl >> 2)) & 3; // swizzled B slot (q-invariant)

  // --- prologue: load x, compute hrev[32] ---
  float hrev[32];
#pragma unroll
  for (int j = 0; j < 8; ++j) {
    f32x4 v = *reinterpret_cast<const f32x4*>(gx + j * 4);
#pragma unroll
    for (int e = 0; e < 4; ++e) {
      float xc = fminf(fmaxf(v[e], -1.0f), 1.0f);
      float wl = __builtin_fmaf(xc, 4.0e-9f, 1550.0e-9f);
      hrev[j * 4 + e] = rc.K2 * xc * fastrcp(wl);
    }
  }

  auto STAGE = [&](int p) {   // 4 gl_lds rounds: 256 B-rows x 32 k of sub-phase p
    const int ring = p >> 1, h = p & 1;
    const int koff = ring * 512 + ks * 64 + h * 32;
    char* base = smB + (p % 3) * 16384 + w * 1024;
#pragma unroll
    for (int iss = 0; iss < 4; ++iss) {
      const int row = iss * 64 + drow;
      const int sg  = (doct - row - (row >> 2)) & 3;   // inverse swizzle
      gl_lds16(Bt + (size_t)(bcol + row) * KTOT + koff + sg * 8,
               base + iss * 4096);
    }
  };
  auto GENA = [&](int ring) {  // A-tile (ring, K=64) into smA[ring&1]
    char* dst = smA + (ring & 1) * 16384;
    if (ring < NRING) {
      const float Frn = rc.Fr[ring];
#pragma unroll
      for (int g = 0; g < 4; ++g) {
        short8 wv;
#pragma unroll
        for (int e = 0; e < 8; ++e) {
          float t = fastfract(hrev[g * 8 + e] + Frn);
          wv[e] = (short)f2bf(fastrcp(cos2pi(t) + rc.SQ));
        }
        *reinterpret_cast<short8*>(dst + wb[g]) = wv;
      }
    } else {                   // residual: reload raw x from L2, pack bf16
#pragma unroll
      for (int g = 0; g < 4; ++g) {
        f32x4 v0 = *reinterpret_cast<const f32x4*>(gx + g * 8);
        f32x4 v1 = *reinterpret_cast<const f32x4*>(gx + g * 8 + 4);
        short8 wv;
#pragma unroll
        for (int e = 0; e < 4; ++e) {
          wv[e]     = (short)f2bf(v0[e]);
          wv[4 + e] = (short)f2bf(v1[e]);
        }
        *reinterpret_cast<short8*>(dst + wb[g]) = wv;
      }
    }
  };

  f32x4 acc[8][4];
#pragma unroll
  for (int m = 0; m < 8; ++m)
#pragma unroll
    for (int q = 0; q < 4; ++q) acc[m][q] = (f32x4){0.f, 0.f, 0.f, 0.f};

  STAGE(0); STAGE(1);
  GENA(0);
  asm volatile("s_waitcnt vmcnt(4) lgkmcnt(0)" ::: "memory");
  __builtin_amdgcn_s_barrier();
  __builtin_amdgcn_sched_barrier(0);

#pragma unroll
  for (int p = 0; p < NPH; ++p) {
    const int ring = p >> 1, h = p & 1;
    const char* bA = smA + (ring & 1) * 16384;
    const char* bB = smB + (p % 3) * 16384;
    short8 af[8], bv[4];
    // A frags: global k-octet (lane>>4)+4h of the ring's K=64 tile
    {
      const int octA = (((lane >> 4) + 4 * h) ^ l7) * 16;
#pragma unroll
      for (int m = 0; m < 8; ++m)
        af[m] = *reinterpret_cast<const short8*>(bA + (rowA + m * 16) * 128 + octA);
    }
#pragma unroll
    for (int q = 0; q < 4; ++q)
      bv[q] = *reinterpret_cast<const short8*>(bB + (rowBl + q * 16) * 64 + olB * 16);
    if (p + 2 < NPH) STAGE(p + 2);
    if (h == 1 && ring + 1 <= NRING) GENA(ring + 1);
    __builtin_amdgcn_s_setprio(1);
#pragma unroll
    for (int m = 0; m < 8; ++m)
#pragma unroll
      for (int q = 0; q < 4; ++q)
        acc[m][q] = __builtin_amdgcn_mfma_f32_16x16x32_bf16(af[m], bv[q], acc[m][q], 0, 0, 0);
    __builtin_amdgcn_s_setprio(0);
    if (p + 1 < NPH) {
      if (p + 2 < NPH) {
        asm volatile("s_waitcnt vmcnt(4) lgkmcnt(0)" ::: "memory");  // B(p+1) landed
      } else {
        asm volatile("s_waitcnt vmcnt(0) lgkmcnt(0)" ::: "memory");  // drain last
      }
      __builtin_amdgcn_s_barrier();
      __builtin_amdgcn_sched_barrier(0);
    }
  }

  // epilogue: bf16 partials
  unsigned short* po = part + (size_t)ks * ((size_t)Bsz * OUTsz);
  const int r0 = brow + ((lane >> 4) * 4);
  const int c0 = bcol + w * 64 + (lane & 15);
#pragma unroll
  for (int m = 0; m < 8; ++m)
#pragma unroll
    for (int q = 0; q < 4; ++q)
#pragma unroll
      for (int e = 0; e < 4; ++e)
        po[(size_t)(r0 + m * 16 + e) * OUTsz + (c0 + q * 16)] = f2bf(acc[m][q][e]);
}

// ---- reduce 8 bf16 split-K partials + bias + kl ----
__global__ __launch_bounds__(256) void reduce_kernel(
    const unsigned short* __restrict__ part, const float* __restrict__ bias,
    float* __restrict__ out) {
  const size_t idx  = (size_t)blockIdx.x * 256 + threadIdx.x;  // unit = 8 outputs
  const size_t base = idx * 8;
  float s[8];
#pragma unroll
  for (int e = 0; e < 8; ++e) s[e] = 0.0f;
#pragma unroll
  for (int sp = 0; sp < SPLITK; ++sp) {
    short8 v = *reinterpret_cast<const short8*>(part + sp * ((size_t)Bsz * OUTsz) + base);
#pragma unroll
    for (int e = 0; e < 8; ++e) s[e] += bf2f((unsigned short)v[e]);
  }
  const int ob = (int)(base & (OUTsz - 1));
  f32x4 b0 = *reinterpret_cast<const f32x4*>(bias + ob);
  f32x4 b1 = *reinterpret_cast<const f32x4*>(bias + ob + 4);
  f32x4 o0 = { s[0] + b0[0], s[1] + b0[1], s[2] + b0[2], s[3] + b0[3] };
  f32x4 o1 = { s[4] + b1[0], s[5] + b1[1], s[6] + b1[2], s[7] + b1[3] };
  *reinterpret_cast<f32x4*>(out + base) = o0;
  *reinterpret_cast<f32x4*>(out + base + 4) = o1;
  if (idx == 0) out[(size_t)Bsz * OUTsz] = 0.0f;   // kl
}

extern "C" void kernel_launch(void* const* d_in, const int* in_sizes, int n_in,
                              void* d_out, int out_size, void* d_ws, size_t ws_size,
                              hipStream_t stream) {
  const float* x      = (const float*)d_in[0];
  const float* coeffs = (const float*)d_in[1];
  const float* bw     = (const float*)d_in[2];
  float* out = (float*)d_out;

  unsigned short* Bt   = (unsigned short*)d_ws;                            // 8,912,896 B
  unsigned short* part = (unsigned short*)((char*)d_ws + (size_t)OUTsz * KTOT * 2);  // 33,554,432 B
  float* bias = (float*)((char*)d_ws + (size_t)OUTsz * KTOT * 2
                                     + (size_t)SPLITK * Bsz * OUTsz * 2);  // 2048 B

  RC rc;
  float PQ;
  {
    const double PI  = 3.14159265358979323846;
    const double Lc  = 2.0 * PI * 30.0e-6;
    const double WL0 = 1550.0e-9;
    const double NG  = 4.2;
    const double Aamp = pow(10.0, -3.0 * (Lc * 100.0) / 20.0);
    const double Rt2  = 0.8;
    const double Rt   = sqrt(Rt2);
    for (int rr = 0; rr < NRING; ++rr) {
      double off  = -PI + rr * (2.0 * PI / 15.0);
      double neff = 2.34 + off * WL0 / (2.0 * PI * Lc);
      double rev0 = (Lc / WL0) * neff;
      rc.Fr[rr] = (float)(rev0 - floor(rev0));
    }
    const double qn = -2.0 * Rt * Aamp;
    const double s  = 1.0 + Rt2 * Aamp * Aamp;
    const double P  = -(1.0 - Aamp * Aamp) * (1.0 - Rt2);
    rc.K2 = (float)(-4.0e-9 * Lc * NG / WL0);
    rc.SQ = (float)(s / qn);
    rc.pad0 = rc.pad1 = 0.f;
    PQ = (float)(P / qn);
  }

  hipFuncSetAttribute(reinterpret_cast<const void*>(gemm_fused_kernel),
                      hipFuncAttributeMaxDynamicSharedMemorySize, 81920);

  hipLaunchKernelGGL(pack_b_kernel, dim3(OUTsz), dim3(512), 0, stream,
                     coeffs, bw, Bt, bias, PQ);
  hipLaunchKernelGGL(gemm_fused_kernel, dim3(512), dim3(256), 81920, stream,
                     x, Bt, part, rc);
  hipLaunchKernelGGL(reduce_kernel, dim3((Bsz * OUTsz / 8) / 256), dim3(256), 0, stream,
                     part, bias, out);
}

// Round 11
// 64.653 us; speedup vs baseline: 1.5671x; 1.5671x over previous
//
#include <hip/hip_runtime.h>
#include <hip/hip_bf16.h>
#include <cmath>
#include <cstdint>

#define Bsz   4096
#define INsz  512
#define OUTsz 512
#define NRING 16
#define KTOT  8704          /* IN*(NR+1): residual folded in as 17th slot */
#define SPLITK 4
#define NPH   34            /* 2 i-halves x 17 rings, K=64 each */

using short8 = __attribute__((ext_vector_type(8))) short;
using f32x4  = __attribute__((ext_vector_type(4))) float;
using f32x16 = __attribute__((ext_vector_type(16))) float;

struct RC {
  float Cr[NRING];    // cos(2*pi*rev0_r)
  float Snr[NRING];   // -sin(2*pi*rev0_r)
  float K2, SQ, pad0, pad1;  // h=K2*xc*rcp(wl); A' = rcp(cph + SQ)
};

__device__ __forceinline__ unsigned short f2bf(float f) {
  __hip_bfloat16 h = __float2bfloat16(f);               // native cvt (RNE)
  return *reinterpret_cast<unsigned short*>(&h);
}
__device__ __forceinline__ float bf2f(unsigned short u) {
  union { unsigned int u; float f; } v; v.u = (unsigned int)u << 16;
  return v.f;
}
__device__ __forceinline__ float fastrcp(float x) {
#if __has_builtin(__builtin_amdgcn_rcpf)
  return __builtin_amdgcn_rcpf(x);
#else
  return 1.0f / x;
#endif
}
__device__ __forceinline__ float fastfract(float x) {
#if __has_builtin(__builtin_amdgcn_fractf)
  return __builtin_amdgcn_fractf(x);
#else
  return x - floorf(x);
#endif
}
__device__ __forceinline__ float cos2pi(float fr) {
#if __has_builtin(__builtin_amdgcn_cosf)
  return __builtin_amdgcn_cosf(fr);
#else
  return __cosf(fr * 6.28318530717958647692f);
#endif
}
__device__ __forceinline__ float sin2pi(float fr) {
#if __has_builtin(__builtin_amdgcn_sinf)
  return __builtin_amdgcn_sinf(fr);
#else
  return __sinf(fr * 6.28318530717958647692f);
#endif
}

__device__ __forceinline__ void gl_lds16(const void* g, void* l) {
  __builtin_amdgcn_global_load_lds(
      (const __attribute__((address_space(1))) void*)g,
      (__attribute__((address_space(3))) void*)l, 16, 0, 0);
}

// ---- pack B'^T: [OUT][KTOT] bf16, k = n*512 + i; also bias[o] = sum coeffs ----
__global__ __launch_bounds__(512) void pack_b_kernel(
    const float* __restrict__ coeffs, const float* __restrict__ bw,
    unsigned short* __restrict__ Bt, float* __restrict__ bias, float PQ) {
  __shared__ float red[8];
  const int o = blockIdx.x;        // 512 blocks
  const int i = threadIdx.x;       // 512 threads
  const float* cp = coeffs + ((size_t)i * OUTsz + o) * NRING;  // 64B contiguous
  unsigned short* row = Bt + (size_t)o * KTOT + i;
  float s = 0.0f;
#pragma unroll
  for (int j = 0; j < 4; ++j) {
    f32x4 v = *reinterpret_cast<const f32x4*>(cp + j * 4);
#pragma unroll
    for (int e = 0; e < 4; ++e) {
      const int n = j * 4 + e;
      s += v[e];
      row[(size_t)n * INsz] = f2bf(PQ * v[e]);
    }
  }
  row[(size_t)NRING * INsz] = f2bf(bw[(size_t)i * OUTsz + o]);  // residual unscaled
#pragma unroll
  for (int off = 32; off > 0; off >>= 1) s += __shfl_down(s, off);
  const int w = i >> 6;
  if ((i & 63) == 0) red[w] = s;
  __syncthreads();
  if (i == 0) {
    float t = 0.0f;
#pragma unroll
    for (int k = 0; k < 8; ++k) t += red[k];
    bias[o] = t;
  }
}

// ---- fused basis-gen + split-K bf16 MFMA GEMM (R4 base + 32x32x16 MFMA) ----
// BM=128 x BN=256, 8 waves (2M x 4N), wave tile 64x64 as 2x2 of 32x32 frags,
// splitK=4, grid 256 = 1 block/CU, 128KB LDS, counted vmcnt(4), 1 barrier/phase.
__global__ __launch_bounds__(512) void gemm_fused_kernel(
    const float* __restrict__ x, const unsigned short* __restrict__ Bt,
    unsigned short* __restrict__ part, RC rc) {
  extern __shared__ char smem[];
  char* smA = smem;            // 2 x 16384
  char* smB = smem + 32768;    // 3 x 32768
  const int tid  = threadIdx.x;
  const int lane = tid & 63;
  const int w    = tid >> 6;
  const int bid  = blockIdx.x;
  const int combo = bid & 7;         // same (cb,ks) -> same XCD (L2-resident Bt slice)
  const int rb   = bid >> 3;         // 0..31
  const int cb   = combo & 1, ks = combo >> 1;
  const int brow = rb * 128, bcol = cb * 256;

  // --- A-gen ownership: row r (0..127), i-quarter q4 (16 i's per thread) ---
  const int r  = tid & 127;
  const int q4 = tid >> 7;           // 0..3
  const int wb0 = r * 128 + (((q4 * 2 + 0) ^ (r & 7)) * 16);
  const int wb1 = r * 128 + (((q4 * 2 + 1) ^ (r & 7)) * 16);

  // --- B staging: pre-swizzled per-lane global source, linear LDS dest ---
  const int cg = (lane & 7) ^ ((lane >> 3) & 7);
  const unsigned short* gb0 = Bt + (size_t)(bcol + w * 8 + (lane >> 3)) * KTOT + cg * 8;

  // --- fragment read geometry: 8 waves = 2M x 4N, wave tile 64x64 ---
  // 32x32x16 frags: row = lane&31, k-octet = kk*2 + (lane>>5), 8 contiguous bf16
  const int wr = w >> 2, wc = w & 3;
  const int l7 = lane & 7;
  const int l5 = lane >> 5;
  const int rowA = wr * 64 + (lane & 31);
  const int rowB = wc * 64 + (lane & 31);

  // --- prologue: ALL x loads + trig(is=0); is=1 trig refreshed at p==16 ---
  float xf0[16], xf1[16], cth[16], sth[16];
  short8 xbf0a, xbf0b, xbf1a, xbf1b;   // raw x as bf16 (residual ring)
  const float* gx = x + (size_t)(brow + r) * INsz + ks * 128 + q4 * 16;
#pragma unroll
  for (int j = 0; j < 4; ++j) {
    f32x4 v0 = *reinterpret_cast<const f32x4*>(gx + j * 4);
    f32x4 v1 = *reinterpret_cast<const f32x4*>(gx + 64 + j * 4);
#pragma unroll
    for (int e = 0; e < 4; ++e) { xf0[j * 4 + e] = v0[e]; xf1[j * 4 + e] = v1[e]; }
  }
#pragma unroll
  for (int c = 0; c < 8; ++c) {
    xbf0a[c] = (short)f2bf(xf0[c]);     xbf0b[c] = (short)f2bf(xf0[c + 8]);
    xbf1a[c] = (short)f2bf(xf1[c]);     xbf1b[c] = (short)f2bf(xf1[c + 8]);
  }
  auto TRIG = [&](const float* xf) {
#pragma unroll
    for (int c = 0; c < 16; ++c) {
      float xc = fminf(fmaxf(xf[c], -1.0f), 1.0f);
      float wl = __builtin_fmaf(xc, 4.0e-9f, 1550.0e-9f);
      float hh = rc.K2 * xc * fastrcp(wl);
      float fr = fastfract(hh);
      cth[c] = cos2pi(fr);
      sth[c] = sin2pi(fr);
    }
  };
  TRIG(xf0);

  auto STAGE = [&](int p) {   // 4 gl_lds: 256 B-rows x 64 k of tile p
    const int is = (p >= 17) ? 1 : 0, n = p - 17 * is;
    const size_t koff = (size_t)(n * 512 + ks * 128 + is * 64);
    char* ldst = smB + (p % 3) * 32768 + w * 1024;
    const unsigned short* src = gb0 + koff;
#pragma unroll
    for (int iss = 0; iss < 4; ++iss)
      gl_lds16(src + (size_t)iss * 64 * KTOT, ldst + iss * 8192);
  };
  auto GENA = [&](int p) {    // generate A-tile of phase p into As[p&1]
    const int is = (p >= 17) ? 1 : 0, n = p - 17 * is;
    char* dst = smA + (p & 1) * 16384;
    if (n < NRING) {
      const float Crn = rc.Cr[n], Snn = rc.Snr[n];
#pragma unroll
      for (int g = 0; g < 2; ++g) {
        short8 wv;
#pragma unroll
        for (int e = 0; e < 8; ++e) {
          float cph = __builtin_fmaf(cth[g * 8 + e], Crn, sth[g * 8 + e] * Snn);
          wv[e] = (short)f2bf(fastrcp(cph + rc.SQ));
        }
        *reinterpret_cast<short8*>(dst + (g ? wb1 : wb0)) = wv;
      }
    } else {                  // residual ring: raw (unclipped) x, pre-packed
      *reinterpret_cast<short8*>(dst + wb0) = is ? xbf1a : xbf0a;
      *reinterpret_cast<short8*>(dst + wb1) = is ? xbf1b : xbf0b;
    }
  };

  f32x16 acc[2][2];
#pragma unroll
  for (int m = 0; m < 2; ++m)
#pragma unroll
    for (int q = 0; q < 2; ++q)
#pragma unroll
      for (int e = 0; e < 16; ++e) acc[m][q][e] = 0.0f;

  STAGE(0); STAGE(1);
  GENA(0);
  asm volatile("s_waitcnt vmcnt(4) lgkmcnt(0)" ::: "memory");
  __builtin_amdgcn_s_barrier();
  __builtin_amdgcn_sched_barrier(0);

#pragma unroll
  for (int p = 0; p < NPH; ++p) {
    if (p + 2 < NPH) STAGE(p + 2);
    if (p == 16) TRIG(xf1);           // refresh trig for is=1 (regs only)
    const char* bA = smA + (p & 1) * 16384;
    const char* bB = smB + (p % 3) * 32768;
    short8 af[4][2], bv[4][2];        // [kk][m/q]
#pragma unroll
    for (int kk = 0; kk < 4; ++kk) {
      const int oct = ((kk * 2 + l5) ^ l7) * 16;
#pragma unroll
      for (int m = 0; m < 2; ++m)
        af[kk][m] = *reinterpret_cast<const short8*>(bA + (rowA + m * 32) * 128 + oct);
#pragma unroll
      for (int q = 0; q < 2; ++q)
        bv[kk][q] = *reinterpret_cast<const short8*>(bB + (rowB + q * 32) * 128 + oct);
    }
    if (p + 1 < NPH) GENA(p + 1);
    __builtin_amdgcn_s_setprio(1);
#pragma unroll
    for (int kk = 0; kk < 4; ++kk)
#pragma unroll
      for (int m = 0; m < 2; ++m)
#pragma unroll
        for (int q = 0; q < 2; ++q)
          acc[m][q] = __builtin_amdgcn_mfma_f32_32x32x16_bf16(af[kk][m], bv[kk][q], acc[m][q], 0, 0, 0);
    __builtin_amdgcn_s_setprio(0);
    if (p + 1 < NPH) {
      if (p + 2 < NPH) {
        asm volatile("s_waitcnt vmcnt(4) lgkmcnt(0)" ::: "memory");  // B(p+1) landed, B(p+2) in flight
      } else {
        asm volatile("s_waitcnt vmcnt(0) lgkmcnt(0)" ::: "memory");  // drain for last phase
      }
      __builtin_amdgcn_s_barrier();
      __builtin_amdgcn_sched_barrier(0);
    }
  }

  // epilogue: bf16 partials. 32x32 C/D: col=lane&31, row=(reg&3)+8(reg>>2)+4(lane>>5)
  unsigned short* po = part + (size_t)ks * ((size_t)Bsz * OUTsz);
  const int r0 = brow + wr * 64 + 4 * l5;
  const int c0 = bcol + wc * 64 + (lane & 31);
#pragma unroll
  for (int m = 0; m < 2; ++m)
#pragma unroll
    for (int q = 0; q < 2; ++q)
#pragma unroll
      for (int reg = 0; reg < 16; ++reg) {
        const int row = r0 + m * 32 + (reg & 3) + 8 * (reg >> 2);
        po[(size_t)row * OUTsz + (c0 + q * 32)] = f2bf(acc[m][q][reg]);
      }
}

// ---- reduce 4 bf16 split-K partials + bias + kl ----
__global__ __launch_bounds__(256) void reduce_kernel(
    const unsigned short* __restrict__ part, const float* __restrict__ bias,
    float* __restrict__ out) {
  const size_t idx  = (size_t)blockIdx.x * 256 + threadIdx.x;  // unit = 8 outputs
  const size_t base = idx * 8;
  float s[8];
#pragma unroll
  for (int e = 0; e < 8; ++e) s[e] = 0.0f;
#pragma unroll
  for (int sp = 0; sp < SPLITK; ++sp) {
    short8 v = *reinterpret_cast<const short8*>(part + sp * ((size_t)Bsz * OUTsz) + base);
#pragma unroll
    for (int e = 0; e < 8; ++e) s[e] += bf2f((unsigned short)v[e]);
  }
  const int ob = (int)(base & (OUTsz - 1));
  f32x4 b0 = *reinterpret_cast<const f32x4*>(bias + ob);
  f32x4 b1 = *reinterpret_cast<const f32x4*>(bias + ob + 4);
  f32x4 o0 = { s[0] + b0[0], s[1] + b0[1], s[2] + b0[2], s[3] + b0[3] };
  f32x4 o1 = { s[4] + b1[0], s[5] + b1[1], s[6] + b1[2], s[7] + b1[3] };
  *reinterpret_cast<f32x4*>(out + base) = o0;
  *reinterpret_cast<f32x4*>(out + base + 4) = o1;
  if (idx == 0) out[(size_t)Bsz * OUTsz] = 0.0f;   // kl
}

extern "C" void kernel_launch(void* const* d_in, const int* in_sizes, int n_in,
                              void* d_out, int out_size, void* d_ws, size_t ws_size,
                              hipStream_t stream) {
  const float* x      = (const float*)d_in[0];
  const float* coeffs = (const float*)d_in[1];
  const float* bw     = (const float*)d_in[2];
  float* out = (float*)d_out;

  unsigned short* Bt   = (unsigned short*)d_ws;                            // 8,912,896 B
  unsigned short* part = (unsigned short*)((char*)d_ws + (size_t)OUTsz * KTOT * 2);  // 16,777,216 B
  float* bias = (float*)((char*)d_ws + (size_t)OUTsz * KTOT * 2
                                     + (size_t)SPLITK * Bsz * OUTsz * 2);  // 2048 B

  RC rc;
  float PQ;
  {
    const double PI  = 3.14159265358979323846;
    const double Lc  = 2.0 * PI * 30.0e-6;
    const double WL0 = 1550.0e-9;
    const double NG  = 4.2;
    const double Aamp = pow(10.0, -3.0 * (Lc * 100.0) / 20.0);
    const double Rt2  = 0.8;
    const double Rt   = sqrt(Rt2);
    for (int rr = 0; rr < NRING; ++rr) {
      double off  = -PI + rr * (2.0 * PI / 15.0);
      double neff = 2.34 + off * WL0 / (2.0 * PI * Lc);
      double rev0 = (Lc / WL0) * neff;
      rc.Cr[rr]  = (float)cos(2.0 * PI * rev0);
      rc.Snr[rr] = (float)(-sin(2.0 * PI * rev0));
    }
    const double qn = -2.0 * Rt * Aamp;
    const double s  = 1.0 + Rt2 * Aamp * Aamp;
    const double P  = -(1.0 - Aamp * Aamp) * (1.0 - Rt2);
    rc.K2 = (float)(-4.0e-9 * Lc * NG / WL0);
    rc.SQ = (float)(s / qn);
    rc.pad0 = rc.pad1 = 0.f;
    PQ = (float)(P / qn);
  }

  hipFuncSetAttribute(reinterpret_cast<const void*>(gemm_fused_kernel),
                      hipFuncAttributeMaxDynamicSharedMemorySize, 131072);

  hipLaunchKernelGGL(pack_b_kernel, dim3(OUTsz), dim3(512), 0, stream,
                     coeffs, bw, Bt, bias, PQ);
  hipLaunchKernelGGL(gemm_fused_kernel, dim3(256), dim3(512), 131072, stream,
                     x, Bt, part, rc);
  hipLaunchKernelGGL(reduce_kernel, dim3((Bsz * OUTsz / 8) / 256), dim3(256), 0, stream,
                     part, bias, out);
}